// Round 3
// baseline (126.486 us; speedup 1.0000x reference)
//
#include <hip/hip_runtime.h>

#define MARGIN 0.2f
#define EPSC 1e-6f

typedef unsigned long long ull;

__device__ inline void acc8(const float4& av, const float4& pv, const float4& nv,
                            float& sap, float& san) {
    float d;
    d = av.x - pv.x + EPSC; sap += d * d;
    d = av.y - pv.y + EPSC; sap += d * d;
    d = av.z - pv.z + EPSC; sap += d * d;
    d = av.w - pv.w + EPSC; sap += d * d;
    d = av.x - nv.x + EPSC; san += d * d;
    d = av.y - nv.y + EPSC; san += d * d;
    d = av.z - nv.z + EPSC; san += d * d;
    d = av.w - nv.w + EPSC; san += d * d;
}

// One 256-wide scan step: lane holds j = j0 + lane*4 + s (s=0..3).
__device__ inline void scan4(const int4& lj, const int4& xj, int li, int myidx,
                             int j0, int& pos, int& neg) {
    if (pos < 0) {
        int m = ((lj.x == li && xj.x != myidx) ? 1 : 0)
              | ((lj.y == li && xj.y != myidx) ? 2 : 0)
              | ((lj.z == li && xj.z != myidx) ? 4 : 0)
              | ((lj.w == li && xj.w != myidx) ? 8 : 0);
        unsigned long long b = __ballot(m != 0);
        if (b) {
            int L  = __ffsll(b) - 1;
            int mL = __shfl(m, L, 64);
            pos = j0 + L * 4 + (__ffs(mL) - 1);
        }
    }
    if (neg < 0) {
        int m = ((lj.x != li) ? 1 : 0) | ((lj.y != li) ? 2 : 0)
              | ((lj.z != li) ? 4 : 0) | ((lj.w != li) ? 8 : 0);
        unsigned long long b = __ballot(m != 0);
        if (b) {
            int L  = __ffsll(b) - 1;
            int mL = __shfl(m, L, 64);
            neg = j0 + L * 4 + (__ffs(mL) - 1);
        }
    }
}

// Generic 64-wide per-row scan (B not a multiple of 256).
__device__ inline void mine_row_64(const int* __restrict__ label,
                                   const int* __restrict__ zidx, int B, int lane,
                                   int li, int myidx, int& pos, int& neg) {
    pos = -1; neg = -1;
    for (int j0 = 0; j0 < B && (pos < 0 || neg < 0); j0 += 64) {
        int j = j0 + lane;
        bool inb = j < B;
        int lj = 0, xj = 0;
        if (inb) { lj = label[j]; xj = zidx[j]; }
        unsigned long long pb = __ballot(inb && lj == li && xj != myidx);
        unsigned long long nb = __ballot(inb && lj != li);
        if (pos < 0 && pb) pos = j0 + __ffsll(pb) - 1;
        if (neg < 0 && nb) neg = j0 + __ffsll(nb) - 1;
    }
}

// Cold path: ALL labels identical -> reference relabels rows [0,k) to -1.
__device__ inline void mine_allsame(const int* __restrict__ zidx, int B, int lane,
                                    int i, int myidx, int& pos, int& neg) {
    int k = B / 100; if (k < 2) k = 2;
    int kk = k < B ? k : B;
    int lo, hi;
    if (i < kk) { lo = 0;  hi = kk; neg = (kk < B) ? kk : -1; }
    else        { lo = kk; hi = B;  neg = 0; }
    pos = -1;
    for (int j0 = lo; j0 < hi && pos < 0; j0 += 64) {
        int j = j0 + lane;
        bool ok = (j < hi) && (zidx[j] != myidx);
        unsigned long long b = __ballot(ok);
        if (b) pos = j0 + __ffsll(b) - 1;
    }
}

// Per-row generic (non-1024) distance path, FP order identical to before.
__device__ inline void row_generic(const float* __restrict__ z, int i, int pi,
                                   int ni, int C, int lane,
                                   float& lsum, float& lcnt, bool valid) {
    const float4* a = (const float4*)(z + (size_t)i  * C) + lane;
    const float4* p = (const float4*)(z + (size_t)pi * C) + lane;
    const float4* n = (const float4*)(z + (size_t)ni * C) + lane;
    float sap = 0.f, san = 0.f;
    const int nk = C >> 8;
    for (int kk = 0; kk < nk; ++kk)
        acc8(a[kk * 64], p[kk * 64], n[kk * 64], sap, san);
    for (int c = (nk << 8) + lane; c < C; c += 64) {
        float av = z[(size_t)i  * C + c];
        float pv = z[(size_t)pi * C + c];
        float nv = z[(size_t)ni * C + c];
        float d = av - pv + EPSC; sap += d * d;
        d = av - nv + EPSC; san += d * d;
    }
    for (int off = 32; off; off >>= 1) {
        sap += __shfl_xor(sap, off, 64);
        san += __shfl_xor(san, off, 64);
    }
    if (lane == 0 && valid) {
        lsum += fmaxf(sqrtf(sap) - sqrtf(san) + MARGIN, 0.f);
        lcnt += 1.f;
    }
}

// -------- Single fused kernel: mine + distances + last-block final reduce ----
// Per wave: 2 rows (same map as before). Mining and FP accumulation order are
// bit-identical to the previously passing version. The last block to finish
// (agent-scope counter) performs the final reduction, emulating the old
// 1024-thread final_kernel with 4 virtual threads per real thread so the FP
// addition tree is bit-identical. Cross-XCD visibility: agent-scope atomics
// on g_part + counter (per-XCD L2s are not coherent).
__global__ __launch_bounds__(256) void triplet_kernel(
    const float* __restrict__ z, const int* __restrict__ label,
    const int* __restrict__ zidx, int B, int C,
    float2* __restrict__ g_part, unsigned* __restrict__ counter,
    float* __restrict__ out, int nblk)
{
    const int wave = threadIdx.x >> 6;
    const int lane = threadIdx.x & 63;
    const int ia = blockIdx.x * 8 + wave * 2;
    const int ib = ia + 1;
    const bool hasA = ia < B, hasB = ib < B;
    const bool fast = (C == 1024) && hasA && hasB;

    float lsum = 0.f, lcnt = 0.f;

    int liA = 0, idxA = 0, liB = 0, idxB = 0;
    if (hasA) { liA = label[ia]; idxA = zidx[ia]; }
    if (hasB) { liB = label[ib]; idxB = zidx[ib]; }

    // preload both anchors; these stay in flight across the mining scan
    float4 A0, A1, A2, A3, B0, B1, B2, B3;
    if (fast) {
        const float4* aA = (const float4*)(z + (size_t)ia * 1024) + lane;
        const float4* aB = (const float4*)(z + (size_t)ib * 1024) + lane;
        A0 = aA[0]; A1 = aA[64]; A2 = aA[128]; A3 = aA[192];
        B0 = aB[0]; B1 = aB[64]; B2 = aB[128]; B3 = aB[192];
    }

    // ---- mining (identical logic to the passing versions) ----
    int posA = -1, negA = -1, posB = -1, negB = -1;
    if (hasA) {
        if ((B & 255) == 0) {
            if (!hasB) { posB = 0; negB = 0; }       // sentinel: already "found"
            for (int j0 = 0; j0 < B && (posA < 0 || negA < 0 || posB < 0 || negB < 0);
                 j0 += 256) {
                const int base = j0 + lane * 4;
                int4 lj = *(const int4*)(label + base);
                int4 xj = *(const int4*)(zidx + base);
                scan4(lj, xj, liA, idxA, j0, posA, negA);
                if (hasB) scan4(lj, xj, liB, idxB, j0, posB, negB);
            }
        } else {
            mine_row_64(label, zidx, B, lane, liA, idxA, posA, negA);
            if (hasB) mine_row_64(label, zidx, B, lane, liB, idxB, posB, negB);
        }
        if (negA < 0) {  // no different label anywhere -> all-same cold path
            mine_allsame(zidx, B, lane, ia, idxA, posA, negA);
            if (hasB) mine_allsame(zidx, B, lane, ib, idxB, posB, negB);
        }
    }

    // ---- distances (identical FP order) ----
    if (fast) {
        const int piA = posA < 0 ? 0 : posA;         // argmax of all-False = 0
        const int niA = negA < 0 ? 0 : negA;
        const int piB = posB < 0 ? 0 : posB;
        const int niB = negB < 0 ? 0 : negB;
        const float4* pA = (const float4*)(z + (size_t)piA * 1024) + lane;
        const float4* nA = (const float4*)(z + (size_t)niA * 1024) + lane;
        const float4* pB = (const float4*)(z + (size_t)piB * 1024) + lane;
        const float4* nB = (const float4*)(z + (size_t)niB * 1024) + lane;

        float4 PA0 = pA[0], PA1 = pA[64], PA2 = pA[128], PA3 = pA[192];
        float4 NA0 = nA[0], NA1 = nA[64], NA2 = nA[128], NA3 = nA[192];
        float4 PB0 = pB[0], PB1 = pB[64], PB2 = pB[128], PB3 = pB[192];
        float4 NB0 = nB[0], NB1 = nB[64], NB2 = nB[128], NB3 = nB[192];

        float sap = 0.f, san = 0.f;
        acc8(A0, PA0, NA0, sap, san); acc8(A1, PA1, NA1, sap, san);
        acc8(A2, PA2, NA2, sap, san); acc8(A3, PA3, NA3, sap, san);
        for (int off = 32; off; off >>= 1) {
            sap += __shfl_xor(sap, off, 64);
            san += __shfl_xor(san, off, 64);
        }
        if (lane == 0 && posA >= 0 && negA >= 0) {
            lsum += fmaxf(sqrtf(sap) - sqrtf(san) + MARGIN, 0.f);
            lcnt += 1.f;
        }

        sap = 0.f; san = 0.f;
        acc8(B0, PB0, NB0, sap, san); acc8(B1, PB1, NB1, sap, san);
        acc8(B2, PB2, NB2, sap, san); acc8(B3, PB3, NB3, sap, san);
        for (int off = 32; off; off >>= 1) {
            sap += __shfl_xor(sap, off, 64);
            san += __shfl_xor(san, off, 64);
        }
        if (lane == 0 && posB >= 0 && negB >= 0) {
            lsum += fmaxf(sqrtf(sap) - sqrtf(san) + MARGIN, 0.f);
            lcnt += 1.f;
        }
    } else {
        if (hasA)
            row_generic(z, ia, posA < 0 ? 0 : posA, negA < 0 ? 0 : negA,
                        C, lane, lsum, lcnt, posA >= 0 && negA >= 0);
        if (hasB)
            row_generic(z, ib, posB < 0 ? 0 : posB, negB < 0 ? 0 : negB,
                        C, lane, lsum, lcnt, posB >= 0 && negB >= 0);
    }

    // ---- block partial + completion counter ----
    __shared__ float s_sum[4], s_cnt[4];
    __shared__ int s_won;
    if (lane == 0) { s_sum[wave] = lsum; s_cnt[wave] = lcnt; }
    __syncthreads();
    if (threadIdx.x == 0) {
        float bs = 0.f, bc = 0.f;
        for (int w = 0; w < 4; ++w) { bs += s_sum[w]; bc += s_cnt[w]; }
        float2 v = make_float2(bs, bc);
        ull u; __builtin_memcpy(&u, &v, 8);
        __hip_atomic_store((ull*)&g_part[blockIdx.x], u,
                           __ATOMIC_RELEASE, __HIP_MEMORY_SCOPE_AGENT);
        __threadfence();
        unsigned old = __hip_atomic_fetch_add(counter, 1u,
                           __ATOMIC_ACQ_REL, __HIP_MEMORY_SCOPE_AGENT);
        s_won = (old == (unsigned)(nblk - 1)) ? 1 : 0;
    }
    __syncthreads();
    if (!s_won) return;

    // ---- final reduction: bit-identical to the old 1024-thread final_kernel.
    // Real thread t emulates virtual threads vt = t + 256*q (q=0..3):
    // virtual lane == real lane, virtual wave == wave + 4q, so the shuffle
    // tree pairing and s_s[0..15] summation order match exactly.
    const int t = threadIdx.x;
    __shared__ float s_s[16], s_c[16];
    for (int q = 0; q < 4; ++q) {
        const int vt = t + 256 * q;
        float s = 0.f, c = 0.f;
        for (int idx = vt; idx < nblk; idx += 1024) {
            ull u = __hip_atomic_load((const ull*)&g_part[idx],
                                      __ATOMIC_RELAXED, __HIP_MEMORY_SCOPE_AGENT);
            float2 v; __builtin_memcpy(&v, &u, 8);
            s += v.x; c += v.y;
        }
        for (int off = 32; off; off >>= 1) {
            s += __shfl_xor(s, off, 64);
            c += __shfl_xor(c, off, 64);
        }
        if (lane == 0) { s_s[vt >> 6] = s; s_c[vt >> 6] = c; }
    }
    __syncthreads();
    if (t == 0) {
        float ts = 0.f, tc = 0.f;
        for (int w = 0; w < 16; ++w) { ts += s_s[w]; tc += s_c[w]; }
        out[0] = (tc > 0.f) ? ts / tc : 0.f;
    }
}

extern "C" void kernel_launch(void* const* d_in, const int* in_sizes, int n_in,
                              void* d_out, int out_size, void* d_ws, size_t ws_size,
                              hipStream_t stream) {
    const int*   z_label = (const int*)d_in[0];
    const int*   z_idx   = (const int*)d_in[1];
    const float* z       = (const float*)d_in[2];
    const int B = in_sizes[0];
    const int C = in_sizes[2] / B;
    float* out = (float*)d_out;

    const int nblk = (B + 7) / 8;       // 2 rows per wave, 4 waves/block
    unsigned* counter = (unsigned*)d_ws;                 // 4 B, zeroed below
    float2* g_part = (float2*)((char*)d_ws + 256);       // per-block partials

    // Workspace is re-poisoned by the harness every iteration, so the counter
    // must be zeroed per launch. hipMemsetAsync is a stream-ordered,
    // graph-capturable op (the harness reset uses it itself).
    hipMemsetAsync(d_ws, 0, 4, stream);
    triplet_kernel<<<nblk, 256, 0, stream>>>(z, z_label, z_idx, B, C,
                                             g_part, counter, out, nblk);
}

// Round 5
// 83.132 us; speedup vs baseline: 1.5215x; 1.5215x over previous
//
#include <hip/hip_runtime.h>

#define MARGIN 0.2f
#define EPSC 1e-6f

__device__ inline void acc8(const float4& av, const float4& pv, const float4& nv,
                            float& sap, float& san) {
    float d;
    d = av.x - pv.x + EPSC; sap += d * d;
    d = av.y - pv.y + EPSC; sap += d * d;
    d = av.z - pv.z + EPSC; sap += d * d;
    d = av.w - pv.w + EPSC; sap += d * d;
    d = av.x - nv.x + EPSC; san += d * d;
    d = av.y - nv.y + EPSC; san += d * d;
    d = av.z - nv.z + EPSC; san += d * d;
    d = av.w - nv.w + EPSC; san += d * d;
}

// One 256-wide scan step: lane holds j = j0 + lane*4 + s (s=0..3).
__device__ inline void scan4(const int4& lj, const int4& xj, int li, int myidx,
                             int j0, int& pos, int& neg) {
    if (pos < 0) {
        int m = ((lj.x == li && xj.x != myidx) ? 1 : 0)
              | ((lj.y == li && xj.y != myidx) ? 2 : 0)
              | ((lj.z == li && xj.z != myidx) ? 4 : 0)
              | ((lj.w == li && xj.w != myidx) ? 8 : 0);
        unsigned long long b = __ballot(m != 0);
        if (b) {
            int L  = __ffsll(b) - 1;
            int mL = __shfl(m, L, 64);
            pos = j0 + L * 4 + (__ffs(mL) - 1);
        }
    }
    if (neg < 0) {
        int m = ((lj.x != li) ? 1 : 0) | ((lj.y != li) ? 2 : 0)
              | ((lj.z != li) ? 4 : 0) | ((lj.w != li) ? 8 : 0);
        unsigned long long b = __ballot(m != 0);
        if (b) {
            int L  = __ffsll(b) - 1;
            int mL = __shfl(m, L, 64);
            neg = j0 + L * 4 + (__ffs(mL) - 1);
        }
    }
}

// Generic 64-wide per-row scan (B not a multiple of 256).
__device__ inline void mine_row_64(const int* __restrict__ label,
                                   const int* __restrict__ zidx, int B, int lane,
                                   int li, int myidx, int& pos, int& neg) {
    pos = -1; neg = -1;
    for (int j0 = 0; j0 < B && (pos < 0 || neg < 0); j0 += 64) {
        int j = j0 + lane;
        bool inb = j < B;
        int lj = 0, xj = 0;
        if (inb) { lj = label[j]; xj = zidx[j]; }
        unsigned long long pb = __ballot(inb && lj == li && xj != myidx);
        unsigned long long nb = __ballot(inb && lj != li);
        if (pos < 0 && pb) pos = j0 + __ffsll(pb) - 1;
        if (neg < 0 && nb) neg = j0 + __ffsll(nb) - 1;
    }
}

// Cold path: ALL labels identical -> reference relabels rows [0,k) to -1.
__device__ inline void mine_allsame(const int* __restrict__ zidx, int B, int lane,
                                    int i, int myidx, int& pos, int& neg) {
    int k = B / 100; if (k < 2) k = 2;
    int kk = k < B ? k : B;
    int lo, hi;
    if (i < kk) { lo = 0;  hi = kk; neg = (kk < B) ? kk : -1; }
    else        { lo = kk; hi = B;  neg = 0; }
    pos = -1;
    for (int j0 = lo; j0 < hi && pos < 0; j0 += 64) {
        int j = j0 + lane;
        bool ok = (j < hi) && (zidx[j] != myidx);
        unsigned long long b = __ballot(ok);
        if (b) pos = j0 + __ffsll(b) - 1;
    }
}

// Per-row generic (non-1024) distance path, FP order identical to fast path.
__device__ inline void row_generic(const float* __restrict__ z, int i, int pi,
                                   int ni, int C, int lane,
                                   float& lsum, float& lcnt, bool valid) {
    const float4* a = (const float4*)(z + (size_t)i  * C) + lane;
    const float4* p = (const float4*)(z + (size_t)pi * C) + lane;
    const float4* n = (const float4*)(z + (size_t)ni * C) + lane;
    float sap = 0.f, san = 0.f;
    const int nk = C >> 8;
    for (int kk = 0; kk < nk; ++kk)
        acc8(a[kk * 64], p[kk * 64], n[kk * 64], sap, san);
    for (int c = (nk << 8) + lane; c < C; c += 64) {
        float av = z[(size_t)i  * C + c];
        float pv = z[(size_t)pi * C + c];
        float nv = z[(size_t)ni * C + c];
        float d = av - pv + EPSC; sap += d * d;
        d = av - nv + EPSC; san += d * d;
    }
    for (int off = 32; off; off >>= 1) {
        sap += __shfl_xor(sap, off, 64);
        san += __shfl_xor(san, off, 64);
    }
    if (lane == 0 && valid) {
        lsum += fmaxf(sqrtf(sap) - sqrtf(san) + MARGIN, 0.f);
        lcnt += 1.f;
    }
}

// -------- Kernel 1: fused mine + distances, ONE row per wave ---------------
// 512 threads = 8 waves; block covers rows [blockIdx*8, blockIdx*8+8) — the
// SAME block->rows map as the previous 4-wave/2-rows-per-wave version, so
// g_part layout is unchanged. Per-wave data is 12 float4 (48 VGPRs), fitting
// the allocator budget so the gathers genuinely stay in flight (round 3
// showed VGPR_Count=48 was serializing the old 24-float4 scheme), and waves
// per CU double for latency hiding. Anchor loads issue before the mining
// scan; their latency hides under it.
__global__ __launch_bounds__(512) void triplet_kernel(
    const float* __restrict__ z, const int* __restrict__ label,
    const int* __restrict__ zidx, int B, int C, float2* __restrict__ g_part)
{
    const int wave = threadIdx.x >> 6;
    const int lane = threadIdx.x & 63;
    const int i = blockIdx.x * 8 + wave;
    const bool hasR = i < B;
    const bool fast = (C == 1024) && hasR;

    float lsum = 0.f, lcnt = 0.f;

    int li = 0, myidx = 0;
    if (hasR) { li = label[i]; myidx = zidx[i]; }

    // anchor preload — stays in flight across the mining scan
    float4 A0, A1, A2, A3;
    if (fast) {
        const float4* a = (const float4*)(z + (size_t)i * 1024) + lane;
        A0 = a[0]; A1 = a[64]; A2 = a[128]; A3 = a[192];
    }

    // ---- mining (identical per-row logic / first-j semantics) ----
    int pos = -1, neg = -1;
    if (hasR) {
        if ((B & 255) == 0) {
            for (int j0 = 0; j0 < B && (pos < 0 || neg < 0); j0 += 256) {
                const int base = j0 + lane * 4;
                int4 lj = *(const int4*)(label + base);
                int4 xj = *(const int4*)(zidx + base);
                scan4(lj, xj, li, myidx, j0, pos, neg);
            }
        } else {
            mine_row_64(label, zidx, B, lane, li, myidx, pos, neg);
        }
        if (neg < 0)  // no different label anywhere -> all-same cold path
            mine_allsame(zidx, B, lane, i, myidx, pos, neg);
    }

    // ---- distances (identical FP order) ----
    if (fast) {
        const int pi = pos < 0 ? 0 : pos;            // argmax of all-False = 0
        const int ni = neg < 0 ? 0 : neg;
        const float4* p = (const float4*)(z + (size_t)pi * 1024) + lane;
        const float4* n = (const float4*)(z + (size_t)ni * 1024) + lane;
        float4 P0 = p[0], P1 = p[64], P2 = p[128], P3 = p[192];
        float4 N0 = n[0], N1 = n[64], N2 = n[128], N3 = n[192];
        float sap = 0.f, san = 0.f;
        acc8(A0, P0, N0, sap, san); acc8(A1, P1, N1, sap, san);
        acc8(A2, P2, N2, sap, san); acc8(A3, P3, N3, sap, san);
        for (int off = 32; off; off >>= 1) {
            sap += __shfl_xor(sap, off, 64);
            san += __shfl_xor(san, off, 64);
        }
        if (lane == 0 && pos >= 0 && neg >= 0) {
            lsum += fmaxf(sqrtf(sap) - sqrtf(san) + MARGIN, 0.f);
            lcnt += 1.f;
        }
    } else if (hasR) {
        row_generic(z, i, pos < 0 ? 0 : pos, neg < 0 ? 0 : neg,
                    C, lane, lsum, lcnt, pos >= 0 && neg >= 0);
    }

    // ---- block partial: replicate the old 4-wave pair tree bit-exactly.
    // Old: wave w held lsum = r(2w) + r(2w+1); bs += lsum sequentially.
    // New: pair_w = (s[2w] + s[2w+1]) (same two floats, same add), then the
    // same sequential accumulation -> identical FP tree -> absmax 0.0.
    __shared__ float s_sum[8], s_cnt[8];
    if (lane == 0) { s_sum[wave] = lsum; s_cnt[wave] = lcnt; }
    __syncthreads();
    if (threadIdx.x == 0) {
        float bs = 0.f, bc = 0.f;
        for (int w = 0; w < 4; ++w) {
            bs += (s_sum[2 * w] + s_sum[2 * w + 1]);
            bc += (s_cnt[2 * w] + s_cnt[2 * w + 1]);
        }
        g_part[blockIdx.x] = make_float2(bs, bc);   // plain store; visibility
    }                                               // via kernel boundary
}

// -------- Kernel 2: reduce partials, write loss (unchanged, bit-exact) ------
__global__ __launch_bounds__(1024) void final_kernel(
    const float2* __restrict__ g_part, int nb, float* __restrict__ out)
{
    const int t = threadIdx.x;
    float s = 0.f, c = 0.f;
    for (int idx = t; idx < nb; idx += blockDim.x) {
        float2 v = g_part[idx];
        s += v.x; c += v.y;
    }
    for (int off = 32; off; off >>= 1) {
        s += __shfl_xor(s, off, 64);
        c += __shfl_xor(c, off, 64);
    }
    __shared__ float s_s[16], s_c[16];
    const int wave = t >> 6, lane = t & 63;
    if (lane == 0) { s_s[wave] = s; s_c[wave] = c; }
    __syncthreads();
    if (t == 0) {
        float ts = 0.f, tc = 0.f;
        const int nw = blockDim.x >> 6;
        for (int w = 0; w < nw; ++w) { ts += s_s[w]; tc += s_c[w]; }
        out[0] = (tc > 0.f) ? ts / tc : 0.f;
    }
}

extern "C" void kernel_launch(void* const* d_in, const int* in_sizes, int n_in,
                              void* d_out, int out_size, void* d_ws, size_t ws_size,
                              hipStream_t stream) {
    const int*   z_label = (const int*)d_in[0];
    const int*   z_idx   = (const int*)d_in[1];
    const float* z       = (const float*)d_in[2];
    const int B = in_sizes[0];
    const int C = in_sizes[2] / B;
    float* out = (float*)d_out;

    const int nblk = (B + 7) / 8;       // 8 rows per block (1 per wave)
    float2* g_part = (float2*)d_ws;

    triplet_kernel<<<nblk, 512, 0, stream>>>(z, z_label, z_idx, B, C, g_part);
    final_kernel<<<1, 1024, 0, stream>>>(g_part, nblk, out);
}